// Round 1
// baseline (284.463 us; speedup 1.0000x reference)
//
#include <hip/hip_runtime.h>
#include <cstdint>
#include <cstddef>

#define EMBED 1024
#define HEAD  128
#define BATCH 4
#define SEQ   4096

typedef __attribute__((ext_vector_type(4))) float f32x4;
typedef __attribute__((ext_vector_type(8))) short s16x8;

__device__ __forceinline__ unsigned short f2bf(float f) {
    union { float f; unsigned u; } v; v.f = f;
    unsigned r = v.u + 0x7fffu + ((v.u >> 16) & 1u);
    return (unsigned short)(r >> 16);
}

// ---- W [1024][128] f32 -> Wt [128][1024] bf16, for the 3 weights (order: q,k,v)
__global__ __launch_bounds__(256) void wt_kernel(const float* __restrict__ Wq,
                                                 const float* __restrict__ Wk,
                                                 const float* __restrict__ Wv,
                                                 unsigned short* __restrict__ Wt) {
    int idx = blockIdx.x * 256 + threadIdx.x;      // 0 .. 393215
    int sel = idx >> 17;                           // 131072 elems per matrix
    int r   = idx & 131071;
    const float* W = (sel == 0) ? Wq : (sel == 1) ? Wk : Wv;
    int h = r >> 10, k = r & 1023;
    Wt[(size_t)sel * 131072 + (size_t)h * EMBED + k] = f2bf(W[(size_t)k * HEAD + h]);
}

// ---- projection GEMM: out[m][n] = sum_k ctx[m][k] * W[k][n], bf16 MFMA
// ctx fp32 [16384][1024]; Wt bf16 [128][1024] (W^T); out bf16 [16384][128]
// tile 128x128, BK=32, 4 waves (2x2), each wave 64x64 = 4x4 16x16 frags
__global__ __launch_bounds__(256) void proj_kernel(const float* __restrict__ ctx,
                                                   const unsigned short* __restrict__ WtAll,
                                                   unsigned short* __restrict__ outAll) {
    __shared__ __align__(16) short As[128 * 40];   // pad 32->40 to break bank conflicts
    __shared__ __align__(16) short Bs[128 * 40];
    const int tid = threadIdx.x;
    const int lane = tid & 63, w = tid >> 6;
    const int wr = w >> 1, wc = w & 1;
    const int lr = lane & 15, lk = lane >> 4;
    const int m0 = blockIdx.x * 128;
    const unsigned short* Wt = WtAll + (size_t)blockIdx.y * 131072;
    unsigned short* outp = outAll + (size_t)blockIdx.y * (size_t)(BATCH * SEQ * HEAD);

    f32x4 zero = {0.f, 0.f, 0.f, 0.f};
    f32x4 acc[4][4];
    #pragma unroll
    for (int i = 0; i < 4; ++i)
        #pragma unroll
        for (int jn = 0; jn < 4; ++jn) acc[i][jn] = zero;

    for (int kk = 0; kk < EMBED; kk += 32) {
        __syncthreads();
        #pragma unroll
        for (int j = 0; j < 2; ++j) {
            int c = tid + j * 256;                 // 512 chunks of 8 elems
            int row = c >> 2, cg = c & 3;
            const float* src = ctx + (size_t)(m0 + row) * EMBED + kk + cg * 8;
            f32x4 x0 = *(const f32x4*)src;
            f32x4 x1 = *(const f32x4*)(src + 4);
            s16x8 cv;
            cv[0] = (short)f2bf(x0[0]); cv[1] = (short)f2bf(x0[1]);
            cv[2] = (short)f2bf(x0[2]); cv[3] = (short)f2bf(x0[3]);
            cv[4] = (short)f2bf(x1[0]); cv[5] = (short)f2bf(x1[1]);
            cv[6] = (short)f2bf(x1[2]); cv[7] = (short)f2bf(x1[3]);
            *(s16x8*)&As[row * 40 + cg * 8] = cv;
            *(s16x8*)&Bs[row * 40 + cg * 8] =
                *(const s16x8*)(Wt + (size_t)row * EMBED + kk + cg * 8);
        }
        __syncthreads();
        s16x8 af[4], bfr[4];
        #pragma unroll
        for (int mi = 0; mi < 4; ++mi)
            af[mi] = *(const s16x8*)&As[(wr * 64 + mi * 16 + lr) * 40 + lk * 8];
        #pragma unroll
        for (int ni = 0; ni < 4; ++ni)
            bfr[ni] = *(const s16x8*)&Bs[(wc * 64 + ni * 16 + lr) * 40 + lk * 8];
        #pragma unroll
        for (int mi = 0; mi < 4; ++mi)
            #pragma unroll
            for (int ni = 0; ni < 4; ++ni)
                acc[mi][ni] = __builtin_amdgcn_mfma_f32_16x16x32_bf16(af[mi], bfr[ni], acc[mi][ni], 0, 0, 0);
    }
    #pragma unroll
    for (int mi = 0; mi < 4; ++mi) {
        int row = m0 + wr * 64 + mi * 16 + lk * 4;
        #pragma unroll
        for (int ni = 0; ni < 4; ++ni) {
            int col = wc * 64 + ni * 16 + lr;
            #pragma unroll
            for (int r = 0; r < 4; ++r)
                outp[(size_t)(row + r) * HEAD + col] = f2bf(acc[mi][ni][r]);
        }
    }
}

// ---- V [B*T][128] bf16 -> Vt [B][128][T] bf16 (so PV B-operand reads are contiguous)
__global__ __launch_bounds__(256) void vt_kernel(const unsigned short* __restrict__ V,
                                                 unsigned short* __restrict__ Vt) {
    __shared__ __align__(16) unsigned short L[64][136];
    const int tid = threadIdx.x;
    const int t0 = blockIdx.x * 64;
    const int b  = t0 >> 12;
    const int tl = t0 & (SEQ - 1);
    #pragma unroll
    for (int j = 0; j < 4; ++j) {
        int c = tid + j * 256;                     // 1024 chunks
        int row = c >> 4, cg = c & 15;
        *(s16x8*)&L[row][cg * 8] =
            *(const s16x8*)(V + (size_t)(t0 + row) * HEAD + cg * 8);
    }
    __syncthreads();
    #pragma unroll
    for (int j = 0; j < 4; ++j) {
        int c = tid + j * 256;
        int h = c >> 3, tg = c & 7;
        s16x8 y;
        #pragma unroll
        for (int e = 0; e < 8; ++e) y[e] = (short)L[tg * 8 + e][h];
        *(s16x8*)(Vt + ((size_t)b * HEAD + h) * SEQ + tl + tg * 8) = y;
    }
}

// ---- flash attention: Q-tile 64 (4 waves x 16 rows), K/V tiles 64, causal
__global__ __launch_bounds__(256) void attn_kernel(const unsigned short* __restrict__ Q,
                                                   const unsigned short* __restrict__ K,
                                                   const unsigned short* __restrict__ Vt,
                                                   float* __restrict__ out) {
    __shared__ __align__(16) short Ks[64 * 136];   // [64 k][128 h] pad->136
    __shared__ __align__(16) short Vs[128 * 72];   // [128 h][64 k] pad->72
    __shared__ __align__(16) short Ps[4][16 * 72]; // per-wave P [16 q][64 k] pad->72
    const int tid = threadIdx.x;
    const int lane = tid & 63, w = tid >> 6;
    const int lr = lane & 15, lk = lane >> 4;
    const int b = blockIdx.x >> 6, qt = blockIdx.x & 63;

    const float kscale = 1.44269504089f * 0.03125f; // log2(e)/sqrt(1024)

    s16x8 qf[4];
    {
        const unsigned short* qbase =
            Q + (size_t)(b * SEQ + qt * 64 + w * 16 + lr) * HEAD + lk * 8;
        #pragma unroll
        for (int kk = 0; kk < 4; ++kk) qf[kk] = *(const s16x8*)(qbase + kk * 32);
    }

    f32x4 zero = {0.f, 0.f, 0.f, 0.f};
    f32x4 o[8];
    #pragma unroll
    for (int i = 0; i < 8; ++i) o[i] = zero;
    float m_r[4], l_r[4];
    #pragma unroll
    for (int r = 0; r < 4; ++r) { m_r[r] = -1e30f; l_r[r] = 0.f; }

    short* pw = &Ps[w][0];

    for (int j = 0; j <= qt; ++j) {
        __syncthreads();                            // previous iter done reading LDS
        #pragma unroll
        for (int t = 0; t < 4; ++t) {
            int c = tid + t * 256;
            int row = c >> 4, cg = c & 15;
            *(s16x8*)&Ks[row * 136 + cg * 8] =
                *(const s16x8*)(K + (size_t)(b * SEQ + j * 64 + row) * HEAD + cg * 8);
        }
        #pragma unroll
        for (int t = 0; t < 4; ++t) {
            int c = tid + t * 256;
            int h = c >> 3, tg = c & 7;
            *(s16x8*)&Vs[h * 72 + tg * 8] =
                *(const s16x8*)(Vt + ((size_t)b * HEAD + h) * SEQ + j * 64 + tg * 8);
        }
        __syncthreads();

        // S = Q K^T  (per wave: 16 q-rows x 64 k-cols)
        f32x4 s[4];
        #pragma unroll
        for (int nt = 0; nt < 4; ++nt) s[nt] = zero;
        #pragma unroll
        for (int kk = 0; kk < 4; ++kk) {
            #pragma unroll
            for (int nt = 0; nt < 4; ++nt) {
                s16x8 kf = *(const s16x8*)&Ks[(nt * 16 + lr) * 136 + kk * 32 + lk * 8];
                s[nt] = __builtin_amdgcn_mfma_f32_16x16x32_bf16(qf[kk], kf, s[nt], 0, 0, 0);
            }
        }

        // scale (+ causal mask on diagonal tile)
        if (j == qt) {
            #pragma unroll
            for (int nt = 0; nt < 4; ++nt)
                #pragma unroll
                for (int r = 0; r < 4; ++r) {
                    int gq = w * 16 + lk * 4 + r;   // q row within 64-tile
                    int gk = nt * 16 + lr;          // k row within 64-tile
                    float sv = s[nt][r] * kscale;
                    s[nt][r] = (gk > gq) ? -1e30f : sv;
                }
        } else {
            #pragma unroll
            for (int nt = 0; nt < 4; ++nt)
                #pragma unroll
                for (int r = 0; r < 4; ++r) s[nt][r] *= kscale;
        }

        // online softmax per q-row (row = lk*4+r lives in the 16 lanes sharing lk)
        #pragma unroll
        for (int r = 0; r < 4; ++r) {
            float v = fmaxf(fmaxf(s[0][r], s[1][r]), fmaxf(s[2][r], s[3][r]));
            v = fmaxf(v, __shfl_xor(v, 1));
            v = fmaxf(v, __shfl_xor(v, 2));
            v = fmaxf(v, __shfl_xor(v, 4));
            v = fmaxf(v, __shfl_xor(v, 8));
            float mn = fmaxf(m_r[r], v);
            float f = exp2f(m_r[r] - mn);
            m_r[r] = mn;
            float rs = 0.f;
            #pragma unroll
            for (int nt = 0; nt < 4; ++nt) {
                float p = exp2f(s[nt][r] - mn);
                s[nt][r] = p;
                rs += p;
            }
            rs += __shfl_xor(rs, 1);
            rs += __shfl_xor(rs, 2);
            rs += __shfl_xor(rs, 4);
            rs += __shfl_xor(rs, 8);
            l_r[r] = l_r[r] * f + rs;
            #pragma unroll
            for (int nt = 0; nt < 8; ++nt) o[nt][r] *= f;
        }

        // P -> per-wave LDS (bf16), then PV
        #pragma unroll
        for (int nt = 0; nt < 4; ++nt)
            #pragma unroll
            for (int r = 0; r < 4; ++r)
                pw[(lk * 4 + r) * 72 + nt * 16 + lr] = (short)f2bf(s[nt][r]);

        #pragma unroll
        for (int ks = 0; ks < 2; ++ks) {
            s16x8 pa = *(const s16x8*)&pw[lr * 72 + ks * 32 + lk * 8];
            #pragma unroll
            for (int nt = 0; nt < 8; ++nt) {
                s16x8 vb = *(const s16x8*)&Vs[(nt * 16 + lr) * 72 + ks * 32 + lk * 8];
                o[nt] = __builtin_amdgcn_mfma_f32_16x16x32_bf16(pa, vb, o[nt], 0, 0, 0);
            }
        }
    }

    float inv[4];
    #pragma unroll
    for (int r = 0; r < 4; ++r) inv[r] = 1.0f / l_r[r];
    float* ob = out + (size_t)(b * SEQ + qt * 64 + w * 16) * HEAD;
    #pragma unroll
    for (int nt = 0; nt < 8; ++nt)
        #pragma unroll
        for (int r = 0; r < 4; ++r)
            ob[(size_t)(lk * 4 + r) * HEAD + nt * 16 + lr] = o[nt][r] * inv[r];
}

extern "C" void kernel_launch(void* const* d_in, const int* in_sizes, int n_in,
                              void* d_out, int out_size, void* d_ws, size_t ws_size,
                              hipStream_t stream) {
    const float* ctx = (const float*)d_in[0];
    const float* Wk  = (const float*)d_in[1];
    const float* Wq  = (const float*)d_in[2];
    const float* Wv  = (const float*)d_in[3];
    float* out = (float*)d_out;

    // workspace layout (shorts): Wt[3*131072] | Q | K | V | Vt (each 2097152)
    unsigned short* Wt  = (unsigned short*)d_ws;
    unsigned short* Qb  = Wt + 3 * 131072;
    unsigned short* Kb  = Qb + 2097152;
    unsigned short* Vb  = Kb + 2097152;
    unsigned short* Vtb = Vb + 2097152;

    wt_kernel<<<1536, 256, 0, stream>>>(Wq, Wk, Wv, Wt);
    proj_kernel<<<dim3(128, 3), 256, 0, stream>>>(ctx, Wt, Qb);
    vt_kernel<<<256, 256, 0, stream>>>(Vb, Vtb);
    attn_kernel<<<256, 256, 0, stream>>>(Qb, Kb, Vtb, out);
}

// Round 3
// 265.841 us; speedup vs baseline: 1.0701x; 1.0701x over previous
//
#include <hip/hip_runtime.h>
#include <cstdint>
#include <cstddef>

#define EMBED 1024
#define HEAD  128
#define BATCH 4
#define SEQ   4096

typedef __attribute__((ext_vector_type(4))) float f32x4;
typedef __attribute__((ext_vector_type(8))) short s16x8;

__device__ __forceinline__ unsigned short f2bf(float f) {
    union { float f; unsigned u; } v; v.f = f;
    unsigned r = v.u + 0x7fffu + ((v.u >> 16) & 1u);
    return (unsigned short)(r >> 16);
}

// ---- W [1024][128] f32 x3 -> Wt [384][1024] bf16 (rows: 0-127 Q, 128-255 K, 256-383 V)
__global__ __launch_bounds__(256) void wt_kernel(const float* __restrict__ Wq,
                                                 const float* __restrict__ Wk,
                                                 const float* __restrict__ Wv,
                                                 unsigned short* __restrict__ Wt) {
    int idx = blockIdx.x * 256 + threadIdx.x;      // 0 .. 393215
    int sel = idx >> 17;                           // 131072 elems per matrix
    int r   = idx & 131071;
    const float* W = (sel == 0) ? Wq : (sel == 1) ? Wk : Wv;
    int h = r >> 10, k = r & 1023;
    Wt[(size_t)(sel * 128 + h) * EMBED + k] = f2bf(W[(size_t)k * HEAD + h]);
}

// ---- fused QKV projection: tile M=64 x N=384, BK=64, 8 waves (2x4)
// ctx fp32 [16384][1024]; Wt bf16 [384][1024]; QKV bf16: Q|K|V each [16384][128] contiguous
__global__ __launch_bounds__(512) void proj_kernel(const float* __restrict__ ctx,
                                                   const unsigned short* __restrict__ Wt,
                                                   unsigned short* __restrict__ QKV) {
    __shared__ __align__(16) short As[64 * 72];    // pad 64->72
    __shared__ __align__(16) short Bs[384 * 72];
    const int tid = threadIdx.x;
    const int lane = tid & 63, w = tid >> 6;
    const int wr = w >> 2, wc = w & 3;             // wave rows 32, cols 96
    const int lr = lane & 15, lk = lane >> 4;
    const int m0 = blockIdx.x * 64;

    f32x4 zero = {0.f, 0.f, 0.f, 0.f};
    f32x4 acc[2][6];
    #pragma unroll
    for (int i = 0; i < 2; ++i)
        #pragma unroll
        for (int jn = 0; jn < 6; ++jn) acc[i][jn] = zero;

    for (int kk = 0; kk < EMBED; kk += 64) {
        __syncthreads();
        // A: 64 rows x 64 k fp32 -> bf16 (512 chunks of 8)
        {
            int row = tid >> 3, cg = tid & 7;
            const float* src = ctx + (size_t)(m0 + row) * EMBED + kk + cg * 8;
            f32x4 x0 = *(const f32x4*)src;
            f32x4 x1 = *(const f32x4*)(src + 4);
            s16x8 cv;
            cv[0] = (short)f2bf(x0[0]); cv[1] = (short)f2bf(x0[1]);
            cv[2] = (short)f2bf(x0[2]); cv[3] = (short)f2bf(x0[3]);
            cv[4] = (short)f2bf(x1[0]); cv[5] = (short)f2bf(x1[1]);
            cv[6] = (short)f2bf(x1[2]); cv[7] = (short)f2bf(x1[3]);
            *(s16x8*)&As[row * 72 + cg * 8] = cv;
        }
        // B: 384 rows x 64 k bf16 (3072 chunks of 8)
        #pragma unroll
        for (int jb = 0; jb < 6; ++jb) {
            int c = tid + jb * 512;
            int row = c >> 3, cg = c & 7;
            *(s16x8*)&Bs[row * 72 + cg * 8] =
                *(const s16x8*)(Wt + (size_t)row * EMBED + kk + cg * 8);
        }
        __syncthreads();
        s16x8 af[2][2], bfr[6][2];
        #pragma unroll
        for (int mi = 0; mi < 2; ++mi)
            #pragma unroll
            for (int k2 = 0; k2 < 2; ++k2)
                af[mi][k2] = *(const s16x8*)&As[(wr * 32 + mi * 16 + lr) * 72 + k2 * 32 + lk * 8];
        #pragma unroll
        for (int ni = 0; ni < 6; ++ni)
            #pragma unroll
            for (int k2 = 0; k2 < 2; ++k2)
                bfr[ni][k2] = *(const s16x8*)&Bs[(wc * 96 + ni * 16 + lr) * 72 + k2 * 32 + lk * 8];
        #pragma unroll
        for (int k2 = 0; k2 < 2; ++k2)
            #pragma unroll
            for (int mi = 0; mi < 2; ++mi)
                #pragma unroll
                for (int ni = 0; ni < 6; ++ni)
                    acc[mi][ni] = __builtin_amdgcn_mfma_f32_16x16x32_bf16(af[mi][k2], bfr[ni][k2], acc[mi][ni], 0, 0, 0);
    }
    #pragma unroll
    for (int mi = 0; mi < 2; ++mi) {
        int row = m0 + wr * 32 + mi * 16 + lk * 4;
        #pragma unroll
        for (int ni = 0; ni < 6; ++ni) {
            int n0 = wc * 96 + ni * 16;
            unsigned short* dst = QKV + (size_t)(n0 >> 7) * 2097152 + (n0 & 127) + lr;
            #pragma unroll
            for (int r = 0; r < 4; ++r)
                dst[(size_t)(row + r) * HEAD] = f2bf(acc[mi][ni][r]);
        }
    }
}

// ---- V [B*T][128] bf16 -> Vt [B][128][T] bf16
__global__ __launch_bounds__(256) void vt_kernel(const unsigned short* __restrict__ V,
                                                 unsigned short* __restrict__ Vt) {
    __shared__ __align__(16) unsigned short L[64][136];
    const int tid = threadIdx.x;
    const int t0 = blockIdx.x * 64;
    const int b  = t0 >> 12;
    const int tl = t0 & (SEQ - 1);
    #pragma unroll
    for (int j = 0; j < 4; ++j) {
        int c = tid + j * 256;
        int row = c >> 4, cg = c & 15;
        *(s16x8*)&L[row][cg * 8] =
            *(const s16x8*)(V + (size_t)(t0 + row) * HEAD + cg * 8);
    }
    __syncthreads();
    #pragma unroll
    for (int j = 0; j < 4; ++j) {
        int c = tid + j * 256;
        int h = c >> 3, tg = c & 7;
        s16x8 y;
        #pragma unroll
        for (int e = 0; e < 8; ++e) y[e] = (short)L[tg * 8 + e][h];
        *(s16x8*)(Vt + ((size_t)b * HEAD + h) * SEQ + tl + tg * 8) = y;
    }
}

// ---- flash attention phase 1: grid 640 = 4 b x {exact (qt, chunk) pairs}
// Q-tile 64 rows (4 waves x 16), KV chunk = up to 16 tiles of 64 keys
// writes unnormalized partial O (f32) + per-row (m, l) in log2 domain
__global__ __launch_bounds__(256) void attn_kernel(const unsigned short* __restrict__ Q,
                                                   const unsigned short* __restrict__ K,
                                                   const unsigned short* __restrict__ Vt,
                                                   float* __restrict__ po,
                                                   float* __restrict__ pml) {
    __shared__ __align__(16) short Ks[64 * 136];
    __shared__ __align__(16) short Vs[128 * 72];
    __shared__ __align__(16) short Ps[4][16 * 72];
    const int tid = threadIdx.x;
    const int lane = tid & 63, w = tid >> 6;
    const int lr = lane & 15, lk = lane >> 4;

    const int b = blockIdx.x / 160;
    const int t = blockIdx.x % 160;
    int qt, c;
    if (t < 16)      { qt = t;                      c = 0; }
    else if (t < 48) { int u = t - 16; qt = 16 + (u >> 1); c = u & 1; }
    else if (t < 96) { int u = t - 48; qt = 32 + u / 3;    c = u - (u / 3) * 3; }
    else             { int u = t - 96; qt = 48 + (u >> 2); c = u & 3; }
    const int j0 = c * 16;
    const int j1 = (qt < j0 + 15) ? qt : (j0 + 15);

    const float kscale = 1.44269504089f * 0.03125f; // log2(e)/sqrt(1024)

    s16x8 qf[4];
    {
        const unsigned short* qbase =
            Q + (size_t)(b * SEQ + qt * 64 + w * 16 + lr) * HEAD + lk * 8;
        #pragma unroll
        for (int kk = 0; kk < 4; ++kk) qf[kk] = *(const s16x8*)(qbase + kk * 32);
    }

    f32x4 zero = {0.f, 0.f, 0.f, 0.f};
    f32x4 o[8];
    #pragma unroll
    for (int i = 0; i < 8; ++i) o[i] = zero;
    float m_r[4], l_r[4];
    #pragma unroll
    for (int r = 0; r < 4; ++r) { m_r[r] = -1e30f; l_r[r] = 0.f; }

    short* pw = &Ps[w][0];

    for (int j = j0; j <= j1; ++j) {
        __syncthreads();
        #pragma unroll
        for (int tt = 0; tt < 4; ++tt) {
            int cc = tid + tt * 256;
            int row = cc >> 4, cg = cc & 15;
            *(s16x8*)&Ks[row * 136 + cg * 8] =
                *(const s16x8*)(K + (size_t)(b * SEQ + j * 64 + row) * HEAD + cg * 8);
        }
        #pragma unroll
        for (int tt = 0; tt < 4; ++tt) {
            int cc = tid + tt * 256;
            int h = cc >> 3, tg = cc & 7;
            *(s16x8*)&Vs[h * 72 + tg * 8] =
                *(const s16x8*)(Vt + ((size_t)b * HEAD + h) * SEQ + j * 64 + tg * 8);
        }
        __syncthreads();

        // S = Q K^T (16 q-rows x 64 k-cols per wave)
        f32x4 s[4];
        #pragma unroll
        for (int nt = 0; nt < 4; ++nt) s[nt] = zero;
        __builtin_amdgcn_s_setprio(1);
        #pragma unroll
        for (int kk = 0; kk < 4; ++kk) {
            #pragma unroll
            for (int nt = 0; nt < 4; ++nt) {
                s16x8 kf = *(const s16x8*)&Ks[(nt * 16 + lr) * 136 + kk * 32 + lk * 8];
                s[nt] = __builtin_amdgcn_mfma_f32_16x16x32_bf16(qf[kk], kf, s[nt], 0, 0, 0);
            }
        }
        __builtin_amdgcn_s_setprio(0);

        if (j == qt) {
            #pragma unroll
            for (int nt = 0; nt < 4; ++nt)
                #pragma unroll
                for (int r = 0; r < 4; ++r) {
                    int gq = w * 16 + lk * 4 + r;
                    int gk = nt * 16 + lr;
                    float sv = s[nt][r] * kscale;
                    s[nt][r] = (gk > gq) ? -1e30f : sv;
                }
        } else {
            #pragma unroll
            for (int nt = 0; nt < 4; ++nt)
                #pragma unroll
                for (int r = 0; r < 4; ++r) s[nt][r] *= kscale;
        }

        #pragma unroll
        for (int r = 0; r < 4; ++r) {
            float v = fmaxf(fmaxf(s[0][r], s[1][r]), fmaxf(s[2][r], s[3][r]));
            v = fmaxf(v, __shfl_xor(v, 1));
            v = fmaxf(v, __shfl_xor(v, 2));
            v = fmaxf(v, __shfl_xor(v, 4));
            v = fmaxf(v, __shfl_xor(v, 8));
            float mn = fmaxf(m_r[r], v);
            float f = exp2f(m_r[r] - mn);
            m_r[r] = mn;
            float rs = 0.f;
            #pragma unroll
            for (int nt = 0; nt < 4; ++nt) {
                float p = exp2f(s[nt][r] - mn);
                s[nt][r] = p;
                rs += p;
            }
            rs += __shfl_xor(rs, 1);
            rs += __shfl_xor(rs, 2);
            rs += __shfl_xor(rs, 4);
            rs += __shfl_xor(rs, 8);
            l_r[r] = l_r[r] * f + rs;
            #pragma unroll
            for (int nt = 0; nt < 8; ++nt) o[nt][r] *= f;
        }

        #pragma unroll
        for (int nt = 0; nt < 4; ++nt)
            #pragma unroll
            for (int r = 0; r < 4; ++r)
                pw[(lk * 4 + r) * 72 + nt * 16 + lr] = (short)f2bf(s[nt][r]);

        __builtin_amdgcn_s_setprio(1);
        #pragma unroll
        for (int ks = 0; ks < 2; ++ks) {
            s16x8 pa = *(const s16x8*)&pw[lr * 72 + ks * 32 + lk * 8];
            #pragma unroll
            for (int nt = 0; nt < 8; ++nt) {
                s16x8 vb = *(const s16x8*)&Vs[(nt * 16 + lr) * 72 + ks * 32 + lk * 8];
                o[nt] = __builtin_amdgcn_mfma_f32_16x16x32_bf16(pa, vb, o[nt], 0, 0, 0);
            }
        }
        __builtin_amdgcn_s_setprio(0);
    }

    // write unnormalized partials
    float* pob = po + ((size_t)((b * 64 + qt) * 4 + c)) * 8192;
    #pragma unroll
    for (int nt = 0; nt < 8; ++nt)
        #pragma unroll
        for (int r = 0; r < 4; ++r)
            pob[(size_t)(w * 16 + lk * 4 + r) * HEAD + nt * 16 + lr] = o[nt][r];
    if (lr == 0) {
        float* pmlb = pml + ((size_t)((b * 64 + qt) * 4 + c)) * 128;
        #pragma unroll
        for (int r = 0; r < 4; ++r) {
            int row = w * 16 + lk * 4 + r;
            pmlb[row * 2]     = m_r[r];
            pmlb[row * 2 + 1] = l_r[r];
        }
    }
}

// ---- combine partials: out[q][h] = sum_c w_c * o_c / sum_c w_c * l_c
__global__ __launch_bounds__(256) void combine_kernel(const float* __restrict__ po,
                                                      const float* __restrict__ pml,
                                                      float* __restrict__ out) {
    const int tid = threadIdx.x;
    const int row = blockIdx.x * 8 + (tid >> 5);   // global q row
    const int l32 = tid & 31;
    const int b = row >> 12, q = row & 4095;
    const int qt = q >> 6, r64 = q & 63;
    const int nc = (qt >> 4) + 1;
    const size_t base = (size_t)((b * 64 + qt) * 4);

    float mv[4], lv[4];
    float M = -1e30f;
    for (int c = 0; c < nc; ++c) {
        const float* p = pml + (base + c) * 128 + r64 * 2;
        mv[c] = p[0]; lv[c] = p[1];
        M = fmaxf(M, mv[c]);
    }
    float L = 0.f;
    f32x4 acc = {0.f, 0.f, 0.f, 0.f};
    for (int c = 0; c < nc; ++c) {
        float wgt = exp2f(mv[c] - M);
        L += wgt * lv[c];
        f32x4 x = *(const f32x4*)(po + (base + c) * 8192 + (size_t)r64 * HEAD + l32 * 4);
        acc[0] += wgt * x[0]; acc[1] += wgt * x[1];
        acc[2] += wgt * x[2]; acc[3] += wgt * x[3];
    }
    float inv = 1.0f / L;
    f32x4 y = {acc[0] * inv, acc[1] * inv, acc[2] * inv, acc[3] * inv};
    *(f32x4*)(out + (size_t)row * HEAD + l32 * 4) = y;
}

extern "C" void kernel_launch(void* const* d_in, const int* in_sizes, int n_in,
                              void* d_out, int out_size, void* d_ws, size_t ws_size,
                              hipStream_t stream) {
    const float* ctx = (const float*)d_in[0];
    const float* Wk  = (const float*)d_in[1];
    const float* Wq  = (const float*)d_in[2];
    const float* Wv  = (const float*)d_in[3];
    float* out = (float*)d_out;

    // ws layout: Wt[384*1024] | Q | K | V | Vt (bf16) | po (f32) | pml (f32)
    unsigned short* Wt  = (unsigned short*)d_ws;
    unsigned short* Qb  = Wt + 3 * 131072;
    unsigned short* Kb  = Qb + 2097152;
    unsigned short* Vb  = Kb + 2097152;
    unsigned short* Vtb = Vb + 2097152;
    float* po  = (float*)(Vtb + 2097152);
    float* pml = po + (size_t)4 * 64 * 4 * 8192;

    wt_kernel<<<1536, 256, 0, stream>>>(Wq, Wk, Wv, Wt);
    proj_kernel<<<256, 512, 0, stream>>>(ctx, Wt, Qb);
    vt_kernel<<<256, 256, 0, stream>>>(Vb, Vtb);
    attn_kernel<<<640, 256, 0, stream>>>(Qb, Kb, Vtb, po, pml);
    combine_kernel<<<2048, 256, 0, stream>>>(po, pml, out);
}

// Round 4
// 175.369 us; speedup vs baseline: 1.6221x; 1.5159x over previous
//
#include <hip/hip_runtime.h>
#include <cstdint>
#include <cstddef>

#define EMBED 1024
#define HEAD  128
#define BATCH 4
#define SEQ   4096
#define KSC   0.04508422f   // log2(e)/sqrt(1024)

typedef __attribute__((ext_vector_type(4))) float f32x4;
typedef __attribute__((ext_vector_type(16))) float f32x16;
typedef __attribute__((ext_vector_type(8))) short s16x8;
typedef __attribute__((ext_vector_type(4))) int i32x4;
typedef __attribute__((ext_vector_type(4))) unsigned short u16x4;

__device__ __forceinline__ unsigned short f2bf(float f) {
    union { float f; unsigned u; } v; v.f = f;
    unsigned r = v.u + 0x7fffu + ((v.u >> 16) & 1u);
    return (unsigned short)(r >> 16);
}

__device__ __forceinline__ int cvtpk(float lo, float hi_) {
    int r;
    asm("v_cvt_pk_bf16_f32 %0, %1, %2" : "=v"(r) : "v"(lo), "v"(hi_));
    return r;
}

// ---- W [1024][128] f32 x3 -> Wt [384][1024] bf16 (rows: 0-127 Q, 128-255 K, 256-383 V)
__global__ __launch_bounds__(256) void wt_kernel(const float* __restrict__ Wq,
                                                 const float* __restrict__ Wk,
                                                 const float* __restrict__ Wv,
                                                 unsigned short* __restrict__ Wt) {
    int idx = blockIdx.x * 256 + threadIdx.x;
    int sel = idx >> 17;
    int r   = idx & 131071;
    const float* W = (sel == 0) ? Wq : (sel == 1) ? Wk : Wv;
    int h = r >> 10, k = r & 1023;
    Wt[(size_t)(sel * 128 + h) * EMBED + k] = f2bf(W[(size_t)k * HEAD + h]);
}

// ---- fused QKV projection: tile M=64 x N=384, BK=64, 8 waves (2x4)
__global__ __launch_bounds__(512) void proj_kernel(const float* __restrict__ ctx,
                                                   const unsigned short* __restrict__ Wt,
                                                   unsigned short* __restrict__ QKV) {
    __shared__ __align__(16) short As[64 * 72];
    __shared__ __align__(16) short Bs[384 * 72];
    const int tid = threadIdx.x;
    const int lane = tid & 63, w = tid >> 6;
    const int wr = w >> 2, wc = w & 3;
    const int lr = lane & 15, lk = lane >> 4;
    const int m0 = blockIdx.x * 64;

    f32x4 zero = {0.f, 0.f, 0.f, 0.f};
    f32x4 acc[2][6];
    #pragma unroll
    for (int i = 0; i < 2; ++i)
        #pragma unroll
        for (int jn = 0; jn < 6; ++jn) acc[i][jn] = zero;

    for (int kk = 0; kk < EMBED; kk += 64) {
        __syncthreads();
        {
            int row = tid >> 3, cg = tid & 7;
            const float* src = ctx + (size_t)(m0 + row) * EMBED + kk + cg * 8;
            f32x4 x0 = *(const f32x4*)src;
            f32x4 x1 = *(const f32x4*)(src + 4);
            s16x8 cv;
            cv[0] = (short)f2bf(x0[0]); cv[1] = (short)f2bf(x0[1]);
            cv[2] = (short)f2bf(x0[2]); cv[3] = (short)f2bf(x0[3]);
            cv[4] = (short)f2bf(x1[0]); cv[5] = (short)f2bf(x1[1]);
            cv[6] = (short)f2bf(x1[2]); cv[7] = (short)f2bf(x1[3]);
            *(s16x8*)&As[row * 72 + cg * 8] = cv;
        }
        #pragma unroll
        for (int jb = 0; jb < 6; ++jb) {
            int c = tid + jb * 512;
            int row = c >> 3, cg = c & 7;
            *(s16x8*)&Bs[row * 72 + cg * 8] =
                *(const s16x8*)(Wt + (size_t)row * EMBED + kk + cg * 8);
        }
        __syncthreads();
        s16x8 af[2][2], bfr[6][2];
        #pragma unroll
        for (int mi = 0; mi < 2; ++mi)
            #pragma unroll
            for (int k2 = 0; k2 < 2; ++k2)
                af[mi][k2] = *(const s16x8*)&As[(wr * 32 + mi * 16 + lr) * 72 + k2 * 32 + lk * 8];
        #pragma unroll
        for (int ni = 0; ni < 6; ++ni)
            #pragma unroll
            for (int k2 = 0; k2 < 2; ++k2)
                bfr[ni][k2] = *(const s16x8*)&Bs[(wc * 96 + ni * 16 + lr) * 72 + k2 * 32 + lk * 8];
        #pragma unroll
        for (int k2 = 0; k2 < 2; ++k2)
            #pragma unroll
            for (int mi = 0; mi < 2; ++mi)
                #pragma unroll
                for (int ni = 0; ni < 6; ++ni)
                    acc[mi][ni] = __builtin_amdgcn_mfma_f32_16x16x32_bf16(af[mi][k2], bfr[ni][k2], acc[mi][ni], 0, 0, 0);
    }
    #pragma unroll
    for (int mi = 0; mi < 2; ++mi) {
        int row = m0 + wr * 32 + mi * 16 + lk * 4;
        #pragma unroll
        for (int ni = 0; ni < 6; ++ni) {
            int n0 = wc * 96 + ni * 16;
            unsigned short* dst = QKV + (size_t)(n0 >> 7) * 2097152 + (n0 & 127) + lr;
            #pragma unroll
            for (int r = 0; r < 4; ++r)
                dst[(size_t)(row + r) * HEAD] = f2bf(acc[mi][ni][r]);
        }
    }
}

// ---- V [B*T][128] bf16 -> Vt [B][128][T] bf16
__global__ __launch_bounds__(256) void vt_kernel(const unsigned short* __restrict__ V,
                                                 unsigned short* __restrict__ Vt) {
    __shared__ __align__(16) unsigned short L[64][136];
    const int tid = threadIdx.x;
    const int t0 = blockIdx.x * 64;
    const int b  = t0 >> 12;
    const int tl = t0 & (SEQ - 1);
    #pragma unroll
    for (int j = 0; j < 4; ++j) {
        int c = tid + j * 256;
        int row = c >> 4, cg = c & 15;
        *(s16x8*)&L[row][cg * 8] =
            *(const s16x8*)(V + (size_t)(t0 + row) * HEAD + cg * 8);
    }
    __syncthreads();
    #pragma unroll
    for (int j = 0; j < 4; ++j) {
        int c = tid + j * 256;
        int h = c >> 3, tg = c & 7;
        s16x8 y;
        #pragma unroll
        for (int e = 0; e < 8; ++e) y[e] = (short)L[tg * 8 + e][h];
        *(s16x8*)(Vt + ((size_t)b * HEAD + h) * SEQ + tl + tg * 8) = y;
    }
}

// ---- flash attention, m214-style: 4 waves x 32 q-rows, 32x32x16 MFMA, swapped QK^T,
// in-register softmax, KV chunks of 256 keys, partials out (bf16 O + f32 m,l)
__global__ __launch_bounds__(256, 2) void attn_kernel(const unsigned short* __restrict__ Q,
                                                      const unsigned short* __restrict__ K,
                                                      const unsigned short* __restrict__ Vt,
                                                      unsigned short* __restrict__ po,
                                                      float* __restrict__ pml) {
    __shared__ __align__(16) char smem[65536];   // 2 bufs x (K 16KB + Vt 16KB), XOR-swizzled
    const int tid = threadIdx.x;
    const int lane = tid & 63, w = tid >> 6;
    const int l31 = lane & 31, hi = lane >> 5;
    const int hi16 = hi << 4;

    const int b = blockIdx.x / 272;
    int t = blockIdx.x % 272;
    int qt = 0, cum = 0;
    while (cum + ((qt >> 1) + 1) <= t) { cum += (qt >> 1) + 1; ++qt; }
    const int c = t - cum;
    const int nj = min(4, 2 * qt + 2 - 4 * c);
    const int kb0 = c * 256;
    const int slot = b * 272 + cum + c;

    // Q fragments in registers: Q[q=l31 (+w*32)][d = dt*16 + hi*8 + e]
    const unsigned short* qp = Q + ((size_t)(b * SEQ + qt * 128 + w * 32 + l31)) * HEAD + hi * 8;
    s16x8 qf[8];
    #pragma unroll
    for (int dt = 0; dt < 8; ++dt) qf[dt] = *(const s16x8*)(qp + dt * 16);

    f32x16 o0, o1, o2, o3;
    #pragma unroll
    for (int r = 0; r < 16; ++r) { o0[r] = 0.f; o1[r] = 0.f; o2[r] = 0.f; o3[r] = 0.f; }
    float m_run = -1e30f, l_run = 0.f;

    const int krow = tid >> 4, kch = tid & 15;   // K stage: 16 rows x 16 chunks per pass
    const int vdr  = tid >> 3, vch = tid & 7;    // V stage: 32 rows x 8 chunks per pass

    s16x8 kst[4], vst[4];
    #pragma unroll
    for (int p = 0; p < 4; ++p) {
        kst[p] = *(const s16x8*)(K + ((size_t)(b * SEQ + kb0 + krow + p * 16)) * HEAD + kch * 8);
        vst[p] = *(const s16x8*)(Vt + ((size_t)(b * HEAD + vdr + p * 32)) * SEQ + kb0 + vch * 8);
    }
    #pragma unroll
    for (int p = 0; p < 4; ++p) {
        int r0 = krow + p * 16;
        *(s16x8*)(smem + r0 * 256 + ((kch * 16) ^ ((r0 & 7) << 4))) = kst[p];
        int d0 = vdr + p * 32;
        *(s16x8*)(smem + 16384 + d0 * 128 + ((vch * 16) ^ ((d0 & 7) << 4))) = vst[p];
    }
    __syncthreads();

    for (int j = 0; j < nj; ++j) {
        const int cur = j & 1;
        const int cb = cur * 32768;
        const int kb = kb0 + j * 64;
        if (j + 1 < nj) {                        // early-issue next-tile loads (T14)
            int kbn = kb + 64;
            #pragma unroll
            for (int p = 0; p < 4; ++p) {
                kst[p] = *(const s16x8*)(K + ((size_t)(b * SEQ + kbn + krow + p * 16)) * HEAD + kch * 8);
                vst[p] = *(const s16x8*)(Vt + ((size_t)(b * HEAD + vdr + p * 32)) * SEQ + kbn + vch * 8);
            }
        }

        // ---- QK^T swapped: st[t][r] = S[k = 32t + crow(r,hi)][q = l31]
        f32x16 st0, st1;
        #pragma unroll
        for (int r = 0; r < 16; ++r) { st0[r] = 0.f; st1[r] = 0.f; }
        const int sw = (l31 & 7) << 4;
        const char* kbase0 = smem + cb + l31 * 256;
        const char* kbase1 = kbase0 + 32 * 256;
        __builtin_amdgcn_s_setprio(1);
        #pragma unroll
        for (int dt = 0; dt < 8; ++dt) {
            s16x8 ka0 = *(const s16x8*)(kbase0 + ((dt * 32 + hi16) ^ sw));
            s16x8 ka1 = *(const s16x8*)(kbase1 + ((dt * 32 + hi16) ^ sw));
            st0 = __builtin_amdgcn_mfma_f32_32x32x16_bf16(ka0, qf[dt], st0, 0, 0, 0);
            st1 = __builtin_amdgcn_mfma_f32_32x32x16_bf16(ka1, qf[dt], st1, 0, 0, 0);
        }
        __builtin_amdgcn_s_setprio(0);

        // ---- causal mask (diagonal tiles only)
        if (4 * c + j >= 2 * qt) {
            const int qg = qt * 128 + w * 32 + l31;
            #pragma unroll
            for (int r = 0; r < 16; ++r) {
                int crow = (r & 3) + 8 * (r >> 2) + 4 * hi;
                if (kb + crow > qg)      st0[r] = -3e37f;
                if (kb + 32 + crow > qg) st1[r] = -3e37f;
            }
        }

        // ---- online softmax, fully in-register (one cross-half shuffle)
        float mx = st0[0];
        #pragma unroll
        for (int r = 1; r < 16; ++r) mx = fmaxf(mx, st0[r]);
        #pragma unroll
        for (int r = 0; r < 16; ++r) mx = fmaxf(mx, st1[r]);
        mx = fmaxf(mx, __shfl_xor(mx, 32));
        float mt = mx * KSC;
        if (!__all(mt <= m_run + 8.0f)) {        // defer-max (T13)
            float mn = fmaxf(m_run, mt);
            float f = exp2f(m_run - mn);
            l_run *= f;
            int fi = __float_as_int(f);
            #pragma unroll
            for (int r = 0; r < 16; ++r) {       // transpose f to reg-domain q
                int srcb = 4 * ((r & 3) + 8 * (r >> 2)) + 16 * hi;
                float fr = __int_as_float(__builtin_amdgcn_ds_bpermute(srcb, fi));
                o0[r] *= fr; o1[r] *= fr; o2[r] *= fr; o3[r] *= fr;
            }
            m_run = mn;
        }
        float rs = 0.f;
        #pragma unroll
        for (int r = 0; r < 16; ++r) {
            st0[r] = exp2f(fmaf(st0[r], KSC, -m_run)); rs += st0[r];
            st1[r] = exp2f(fmaf(st1[r], KSC, -m_run)); rs += st1[r];
        }
        rs += __shfl_xor(rs, 32);
        l_run += rs;

        // ---- P -> bf16 PV A-frags in-register (T12: cvt_pk + permlane32_swap)
        int a0 = cvtpk(st0[0], st0[1]),   b0 = cvtpk(st0[4], st0[5]);
        int a1 = cvtpk(st0[2], st0[3]),   b1 = cvtpk(st0[6], st0[7]);
        int a2 = cvtpk(st0[8], st0[9]),   b2 = cvtpk(st0[12], st0[13]);
        int a3 = cvtpk(st0[10], st0[11]), b3 = cvtpk(st0[14], st0[15]);
        int a4 = cvtpk(st1[0], st1[1]),   b4 = cvtpk(st1[4], st1[5]);
        int a5 = cvtpk(st1[2], st1[3]),   b5 = cvtpk(st1[6], st1[7]);
        int a6 = cvtpk(st1[8], st1[9]),   b6 = cvtpk(st1[12], st1[13]);
        int a7 = cvtpk(st1[10], st1[11]), b7 = cvtpk(st1[14], st1[15]);
        asm volatile("v_permlane32_swap_b32 %0, %1" : "+v"(a0), "+v"(b0));
        asm volatile("v_permlane32_swap_b32 %0, %1" : "+v"(a1), "+v"(b1));
        asm volatile("v_permlane32_swap_b32 %0, %1" : "+v"(a2), "+v"(b2));
        asm volatile("v_permlane32_swap_b32 %0, %1" : "+v"(a3), "+v"(b3));
        asm volatile("v_permlane32_swap_b32 %0, %1" : "+v"(a4), "+v"(b4));
        asm volatile("v_permlane32_swap_b32 %0, %1" : "+v"(a5), "+v"(b5));
        asm volatile("v_permlane32_swap_b32 %0, %1" : "+v"(a6), "+v"(b6));
        asm volatile("v_permlane32_swap_b32 %0, %1" : "+v"(a7), "+v"(b7));
        i32x4 pw0 = {a0, a1, b0, b1}; s16x8 pa0 = *(s16x8*)&pw0;
        i32x4 pw1 = {a2, a3, b2, b3}; s16x8 pa1 = *(s16x8*)&pw1;
        i32x4 pw2 = {a4, a5, b4, b5}; s16x8 pa2 = *(s16x8*)&pw2;
        i32x4 pw3 = {a6, a7, b6, b7}; s16x8 pa3 = *(s16x8*)&pw3;

        // ---- PV: o[nt] += P(32x64) * V(64 x 32d-tile)
        __builtin_amdgcn_s_setprio(1);
        #define PV_NT(oo, nt) { \
            const int vr = (nt) * 32 + l31; \
            const int vsw = (vr & 7) << 4; \
            const char* vb = smem + cb + 16384 + vr * 128; \
            oo = __builtin_amdgcn_mfma_f32_32x32x16_bf16(pa0, *(const s16x8*)(vb + ((0  + hi16) ^ vsw)), oo, 0, 0, 0); \
            oo = __builtin_amdgcn_mfma_f32_32x32x16_bf16(pa1, *(const s16x8*)(vb + ((32 + hi16) ^ vsw)), oo, 0, 0, 0); \
            oo = __builtin_amdgcn_mfma_f32_32x32x16_bf16(pa2, *(const s16x8*)(vb + ((64 + hi16) ^ vsw)), oo, 0, 0, 0); \
            oo = __builtin_amdgcn_mfma_f32_32x32x16_bf16(pa3, *(const s16x8*)(vb + ((96 + hi16) ^ vsw)), oo, 0, 0, 0); }
        PV_NT(o0, 0) PV_NT(o1, 1) PV_NT(o2, 2) PV_NT(o3, 3)
        #undef PV_NT
        __builtin_amdgcn_s_setprio(0);

        if (j + 1 < nj) {                        // write next tile into other buffer
            const int nb = (cur ^ 1) * 32768;
            #pragma unroll
            for (int p = 0; p < 4; ++p) {
                int r0 = krow + p * 16;
                *(s16x8*)(smem + nb + r0 * 256 + ((kch * 16) ^ ((r0 & 7) << 4))) = kst[p];
                int d0 = vdr + p * 32;
                *(s16x8*)(smem + nb + 16384 + d0 * 128 + ((vch * 16) ^ ((d0 & 7) << 4))) = vst[p];
            }
        }
        __syncthreads();
    }

    // ---- write partials: O is q=crow(reg), d=lane
    unsigned short* pob = po + (size_t)slot * 16384;
    #define STORE_NT(oo, nt) { \
        _Pragma("unroll") \
        for (int r = 0; r < 16; ++r) { \
            int qin = w * 32 + (r & 3) + 8 * (r >> 2) + 4 * hi; \
            pob[qin * 128 + (nt) * 32 + l31] = f2bf(oo[r]); \
        } }
    STORE_NT(o0, 0) STORE_NT(o1, 1) STORE_NT(o2, 2) STORE_NT(o3, 3)
    #undef STORE_NT
    if (lane < 32) {
        float* pm = pml + (size_t)slot * 256 + (w * 32 + lane) * 2;
        pm[0] = m_run; pm[1] = l_run;
    }
}

// ---- combine partials: out[q][:] = sum_c w_c*O_c / sum_c w_c*l_c
__global__ __launch_bounds__(256) void combine_kernel(const unsigned short* __restrict__ po,
                                                      const float* __restrict__ pml,
                                                      float* __restrict__ out) {
    const int tid = threadIdx.x;
    const int row = blockIdx.x * 8 + (tid >> 5);
    const int l32 = tid & 31;
    const int b = row >> 12, q = row & 4095;
    const int qt = q >> 7, qr = q & 127;
    const int nc = (q >> 8) + 1;
    const int cum = ((qt >> 1) + (qt & 1)) * ((qt >> 1) + 1);
    const size_t bslot = (size_t)b * 272 + cum;

    float M = -1e30f;
    for (int cc = 0; cc < nc; ++cc)
        M = fmaxf(M, pml[(bslot + cc) * 256 + qr * 2]);
    float L = 0.f;
    f32x4 acc = {0.f, 0.f, 0.f, 0.f};
    for (int cc = 0; cc < nc; ++cc) {
        const float* pm = pml + (bslot + cc) * 256 + qr * 2;
        float wgt = exp2f(pm[0] - M);
        L += wgt * pm[1];
        u16x4 x = *(const u16x4*)(po + (bslot + cc) * 16384 + qr * 128 + l32 * 4);
        #pragma unroll
        for (int e = 0; e < 4; ++e) {
            union { unsigned u; float f; } cv; cv.u = ((unsigned)x[e]) << 16;
            acc[e] += wgt * cv.f;
        }
    }
    float inv = 1.f / L;
    f32x4 y = {acc[0] * inv, acc[1] * inv, acc[2] * inv, acc[3] * inv};
    *(f32x4*)(out + (size_t)row * HEAD + l32 * 4) = y;
}

extern "C" void kernel_launch(void* const* d_in, const int* in_sizes, int n_in,
                              void* d_out, int out_size, void* d_ws, size_t ws_size,
                              hipStream_t stream) {
    const float* ctx = (const float*)d_in[0];
    const float* Wk  = (const float*)d_in[1];
    const float* Wq  = (const float*)d_in[2];
    const float* Wv  = (const float*)d_in[3];
    float* out = (float*)d_out;

    // ws (shorts): Wt[393216] | Q | K | V | Vt (2097152 each) | po u16[1088*16384] | pml f32
    unsigned short* Wt  = (unsigned short*)d_ws;
    unsigned short* Qb  = Wt + 3 * 131072;
    unsigned short* Kb  = Qb + 2097152;
    unsigned short* Vb  = Kb + 2097152;
    unsigned short* Vtb = Vb + 2097152;
    unsigned short* po  = Vtb + 2097152;
    float* pml = (float*)(po + (size_t)1088 * 16384);

    wt_kernel<<<1536, 256, 0, stream>>>(Wq, Wk, Wv, Wt);
    proj_kernel<<<256, 512, 0, stream>>>(ctx, Wt, Qb);
    vt_kernel<<<256, 256, 0, stream>>>(Vb, Vtb);
    attn_kernel<<<1088, 256, 0, stream>>>(Qb, Kb, Vtb, po, pml);
    combine_kernel<<<2048, 256, 0, stream>>>(po, pml, out);
}